// Round 4
// baseline (4176.660 us; speedup 1.0000x reference)
//
#include <hip/hip_runtime.h>
#include <cstdint>

typedef __bf16  bf16x8  __attribute__((ext_vector_type(8)));
typedef short   short8v __attribute__((ext_vector_type(8)));
typedef float   f32x4   __attribute__((ext_vector_type(4)));

constexpr int N  = 262144;   // 2^18 voxels
constexpr int C  = 128;
constexpr int K  = 27;
constexpr int M  = 131072;   // 2^17 pairs per offset
constexpr int KM = K * M;    // 3,538,944
constexpr int BR = 64;       // rows per gemm tile
constexpr int TILES_PER_K = M / BR;   // 2048

__device__ __forceinline__ uint16_t f2bf(float f) {
    union { float f; uint32_t u; } x; x.f = f;
    uint32_t r = (x.u + 0x7FFFu + ((x.u >> 16) & 1u)) >> 16;  // RNE
    return (uint16_t)r;
}
__device__ __forceinline__ float bf2f(uint16_t u) {
    union { uint32_t u; float f; } x; x.u = ((uint32_t)u) << 16;
    return x.f;
}

// packed bf16x2 atomic add (fire-and-forget, device scope)
__device__ __forceinline__ void atomic_pk_add_bf16(uint16_t* p, uint32_t v) {
    asm volatile("global_atomic_pk_add_bf16 %0, %1, off" : : "v"(p), "v"(v) : "memory");
}

// ---------- feats f32 -> bf16 ----------
__global__ __launch_bounds__(256) void cast_feats_kernel(
    const float* __restrict__ in, uint16_t* __restrict__ out) {
    int i = blockIdx.x * 256 + threadIdx.x;        // 8 elems per thread
    const float4* src = reinterpret_cast<const float4*>(in) + (size_t)i * 2;
    float4 a = src[0], b = src[1];
    union { uint16_t u[8]; short8v v; } r;
    r.u[0]=f2bf(a.x); r.u[1]=f2bf(a.y); r.u[2]=f2bf(a.z); r.u[3]=f2bf(a.w);
    r.u[4]=f2bf(b.x); r.u[5]=f2bf(b.y); r.u[6]=f2bf(b.z); r.u[7]=f2bf(b.w);
    *(reinterpret_cast<short8v*>(out) + i) = r.v;
}

// ---------- W[k][cin][cout] f32 -> WT[k][cout][cin] bf16 ----------
__global__ __launch_bounds__(256) void transpose_w_kernel(
    const float* __restrict__ W1, const float* __restrict__ W2,
    uint16_t* __restrict__ WT1, uint16_t* __restrict__ WT2) {
    int i = blockIdx.x * 256 + threadIdx.x;        // K*C*C = 442368
    int k    = i / (C * C);
    int rem  = i - k * (C * C);
    int cout = rem >> 7;
    int cin  = rem & 127;
    int src  = k * C * C + cin * C + cout;
    WT1[i] = f2bf(W1[src]);
    WT2[i] = f2bf(W2[src]);
}

// ========== per-k counting sort of pairs by out row ==========
__global__ __launch_bounds__(256) void hist_kernel(
    const int* __restrict__ out_maps, int* __restrict__ counts) {
    int i = blockIdx.x * 256 + threadIdx.x;        // over KM
    int k = i >> 17;                               // M = 2^17
    atomicAdd(&counts[k * N + out_maps[i]], 1);
}

__global__ __launch_bounds__(256) void scan1_kernel(
    const int* __restrict__ counts, int* __restrict__ row_start, int* __restrict__ bsum) {
    __shared__ int lds[256];
    int t = threadIdx.x;
    int k   = blockIdx.x >> 8;                     // 256 blocks per k
    int blk = blockIdx.x & 255;
    int base = k * N + blk * 1024 + t * 4;
    int4 c = *reinterpret_cast<const int4*>(counts + base);
    int tot = c.x + c.y + c.z + c.w;
    lds[t] = tot;
    __syncthreads();
    for (int off = 1; off < 256; off <<= 1) {
        int v = (t >= off) ? lds[t - off] : 0;
        __syncthreads();
        lds[t] += v;
        __syncthreads();
    }
    int excl = lds[t] - tot;
    int4 o;
    o.x = excl; o.y = excl + c.x; o.z = o.y + c.y; o.w = o.z + c.z;
    *reinterpret_cast<int4*>(row_start + base) = o;
    if (t == 255) bsum[blockIdx.x] = lds[255];     // bsum[k*256+blk]
}

__global__ void scan2_kernel(int* __restrict__ bsum) {   // grid = K blocks
    __shared__ int lds[256];
    int t = threadIdx.x;
    int base = blockIdx.x * 256 + t;
    int v0 = bsum[base];
    lds[t] = v0;
    __syncthreads();
    for (int off = 1; off < 256; off <<= 1) {
        int v = (t >= off) ? lds[t - off] : 0;
        __syncthreads();
        lds[t] += v;
        __syncthreads();
    }
    bsum[base] = lds[t] - v0;   // exclusive
}

__global__ __launch_bounds__(256) void scan3_kernel(
    int* __restrict__ row_start, const int* __restrict__ bsum) {
    int i = blockIdx.x * 256 + threadIdx.x;        // over K*N
    int k   = i >> 18;                             // N = 2^18
    int win = i & (N - 1);
    row_start[i] += bsum[(k << 8) + (win >> 10)];
}

__global__ __launch_bounds__(256) void scatter_kernel(
    const int* __restrict__ in_maps, const int* __restrict__ out_maps,
    int* __restrict__ row_start,     // destroyed (used as cursor)
    int2* __restrict__ sInOut) {
    int i = blockIdx.x * 256 + threadIdx.x;        // over KM
    int k = i >> 17;
    int o = out_maps[i];
    int pos = atomicAdd(&row_start[k * N + o], 1); // within-k rank
    int2 v; v.x = in_maps[i]; v.y = o;
    sInOut[k * M + pos] = v;
}

// ========== gather -> MFMA GEMM -> sorted pk-bf16 atomic scatter ==========
__global__ __launch_bounds__(256, 3) void gemm_kernel(
    const uint16_t* __restrict__ featsB,   // [N][C] bf16 input table
    const uint16_t* __restrict__ WT,       // [K][Cout][Cin] bf16
    const int2* __restrict__ sInOut,       // [K*M] sorted (in_row, out_row)
    uint16_t* __restrict__ outB)           // [N][C] bf16 accumulator
{
    __shared__ char lds[BR * C * 2 + C * C * 2];   // A 16KB + W 32KB
    char* Alds = lds;
    char* Wlds = lds + BR * C * 2;

    const int tile = blockIdx.x;
    const int k    = tile >> 11;           // TILES_PER_K = 2048
    const int m0   = (tile & 2047) * BR;
    const int tid  = threadIdx.x;
    const int2* so = sInOut + k * M + m0;

    // stage A: gather 64 rows x 128 ch bf16, XOR-swizzled
    #pragma unroll
    for (int i = 0; i < 4; ++i) {
        int chunk = tid + 256 * i;
        int row   = chunk >> 4;
        int c8    = chunk & 15;
        int g     = so[row].x;
        short8v v = *reinterpret_cast<const short8v*>(featsB + (size_t)g * C + c8 * 8);
        int off = (row * 256 + c8 * 16) ^ ((row & 7) << 4);
        *reinterpret_cast<short8v*>(Alds + off) = v;
    }
    // stage W[k]
    const uint16_t* w = WT + k * C * C;
    #pragma unroll
    for (int i = 0; i < 8; ++i) {
        int chunk = tid + 256 * i;
        int cout  = chunk >> 4;
        int c8    = chunk & 15;
        short8v v = *reinterpret_cast<const short8v*>(w + chunk * 8);
        int off = (cout * 256 + c8 * 16) ^ ((cout & 7) << 4);
        *reinterpret_cast<short8v*>(Wlds + off) = v;
    }
    __syncthreads();

    const int wave  = tid >> 6;
    const int lane  = tid & 63;
    const int r16   = lane & 15;
    const int khalf = lane >> 4;

    short8v a[4];
    {
        int row  = wave * 16 + r16;
        int base = row * 256;
        int swz  = (row & 7) << 4;
        #pragma unroll
        for (int kk = 0; kk < 4; ++kk)
            a[kk] = *reinterpret_cast<const short8v*>(Alds + ((base + kk * 64 + khalf * 16) ^ swz));
    }

    f32x4 acc[8];
    #pragma unroll
    for (int t = 0; t < 8; ++t) acc[t] = (f32x4){0.f, 0.f, 0.f, 0.f};

    #pragma unroll
    for (int t = 0; t < 8; ++t) {
        int col  = t * 16 + r16;
        int base = col * 256;
        int swz  = (col & 7) << 4;
        #pragma unroll
        for (int kk = 0; kk < 4; ++kk) {
            short8v b = *reinterpret_cast<const short8v*>(Wlds + ((base + kk * 64 + khalf * 16) ^ swz));
            acc[t] = __builtin_amdgcn_mfma_f32_16x16x32_bf16(
                __builtin_bit_cast(bf16x8, a[kk]), __builtin_bit_cast(bf16x8, b), acc[t], 0, 0, 0);
        }
    }

    // epilogue: D col=r16, row=khalf*4+j. Pair adjacent channels via shfl,
    // even lanes issue packed bf16 atomics (2 ch / op).
    const int2* sorow = so + wave * 16 + khalf * 4;
    #pragma unroll
    for (int j = 0; j < 4; ++j) {
        int orow = sorow[j].y;
        uint16_t* dst = outB + (size_t)orow * C + r16;
        #pragma unroll
        for (int t = 0; t < 8; ++t) {
            float vlo = acc[t][j];
            float vhi = __shfl_xor(vlo, 1, 64);     // partner channel (r16^1)
            if (!(r16 & 1)) {
                uint32_t pk = (uint32_t)f2bf(vlo) | ((uint32_t)f2bf(vhi) << 16);
                atomic_pk_add_bf16(dst + t * 16, pk);
            }
        }
    }
}

// ---------- per-channel sum & sumsq from bf16 table ----------
__global__ __launch_bounds__(256) void stats_kernel(
    const uint16_t* __restrict__ x, float* __restrict__ sums) {
    const int tid = threadIdx.x;
    const int cg = tid & 15;          // 8-channel group
    const int rg = tid >> 4;          // 0..15
    constexpr int RPB = N / 1024;     // 256 rows per block
    float s[8] = {0,0,0,0,0,0,0,0}, q[8] = {0,0,0,0,0,0,0,0};
    const uint16_t* base = x + (size_t)blockIdx.x * RPB * C + cg * 8;
    for (int r = rg; r < RPB; r += 16) {
        short8v v = *reinterpret_cast<const short8v*>(base + (size_t)r * C);
        #pragma unroll
        for (int i = 0; i < 8; ++i) {
            float f = bf2f((uint16_t)(unsigned short)v[i]);
            s[i] += f; q[i] += f * f;
        }
    }
    __shared__ float red[16][16][8];
    #pragma unroll
    for (int i = 0; i < 8; ++i) red[rg][cg][i] = s[i];
    __syncthreads();
    if (rg == 0) {
        float t8[8];
        #pragma unroll
        for (int i = 0; i < 8; ++i) t8[i] = red[0][cg][i];
        #pragma unroll
        for (int j = 1; j < 16; ++j)
            #pragma unroll
            for (int i = 0; i < 8; ++i) t8[i] += red[j][cg][i];
        #pragma unroll
        for (int i = 0; i < 8; ++i) unsafeAtomicAdd(&sums[cg * 8 + i], t8[i]);
    }
    __syncthreads();
    #pragma unroll
    for (int i = 0; i < 8; ++i) red[rg][cg][i] = q[i];
    __syncthreads();
    if (rg == 0) {
        float t8[8];
        #pragma unroll
        for (int i = 0; i < 8; ++i) t8[i] = red[0][cg][i];
        #pragma unroll
        for (int j = 1; j < 16; ++j)
            #pragma unroll
            for (int i = 0; i < 8; ++i) t8[i] += red[j][cg][i];
        #pragma unroll
        for (int i = 0; i < 8; ++i) unsafeAtomicAdd(&sums[C + cg * 8 + i], t8[i]);
    }
}

__global__ void finalize_kernel(const float* __restrict__ sums,
                                const float* __restrict__ gamma, const float* __restrict__ beta,
                                float* __restrict__ ss) {
    int c = threadIdx.x;
    float m  = sums[c] * (1.0f / N);
    float v  = sums[C + c] * (1.0f / N) - m * m;
    float r  = rsqrtf(v + 1e-5f);
    float sc = gamma[c] * r;
    ss[c]     = sc;
    ss[C + c] = beta[c] - m * sc;
}

// ---------- BN1 + ReLU (bf16 in -> bf16 out) ----------
__global__ __launch_bounds__(256) void bnrelu_kernel(
    const uint16_t* __restrict__ x, const float* __restrict__ ss, uint16_t* __restrict__ out) {
    int i = blockIdx.x * 256 + threadIdx.x;   // 8 ch per thread
    int base = i * 8;
    int c = base & 127;
    float4 sc0 = *reinterpret_cast<const float4*>(ss + c);
    float4 sc1 = *reinterpret_cast<const float4*>(ss + c + 4);
    float4 sh0 = *reinterpret_cast<const float4*>(ss + C + c);
    float4 sh1 = *reinterpret_cast<const float4*>(ss + C + c + 4);
    short8v v = *reinterpret_cast<const short8v*>(x + base);
    float f[8];
    #pragma unroll
    for (int j = 0; j < 8; ++j) f[j] = bf2f((uint16_t)(unsigned short)v[j]);
    union { uint16_t u[8]; short8v v; } r;
    r.u[0] = f2bf(fmaxf(fmaf(f[0], sc0.x, sh0.x), 0.f));
    r.u[1] = f2bf(fmaxf(fmaf(f[1], sc0.y, sh0.y), 0.f));
    r.u[2] = f2bf(fmaxf(fmaf(f[2], sc0.z, sh0.z), 0.f));
    r.u[3] = f2bf(fmaxf(fmaf(f[3], sc0.w, sh0.w), 0.f));
    r.u[4] = f2bf(fmaxf(fmaf(f[4], sc1.x, sh1.x), 0.f));
    r.u[5] = f2bf(fmaxf(fmaf(f[5], sc1.y, sh1.y), 0.f));
    r.u[6] = f2bf(fmaxf(fmaf(f[6], sc1.z, sh1.z), 0.f));
    r.u[7] = f2bf(fmaxf(fmaf(f[7], sc1.w, sh1.w), 0.f));
    *(reinterpret_cast<short8v*>(out) + i) = r.v;
}

// ---------- BN2 + residual + ReLU -> f32 d_out ----------
__global__ __launch_bounds__(256) void final_kernel(
    const uint16_t* __restrict__ xB, const float* __restrict__ feats,
    const float* __restrict__ ss, float* __restrict__ out) {
    int i = blockIdx.x * 256 + threadIdx.x;   // 8 ch per thread
    int base = i * 8;
    int c = base & 127;
    float4 sc0 = *reinterpret_cast<const float4*>(ss + c);
    float4 sc1 = *reinterpret_cast<const float4*>(ss + c + 4);
    float4 sh0 = *reinterpret_cast<const float4*>(ss + C + c);
    float4 sh1 = *reinterpret_cast<const float4*>(ss + C + c + 4);
    short8v v = *reinterpret_cast<const short8v*>(xB + base);
    float f[8];
    #pragma unroll
    for (int j = 0; j < 8; ++j) f[j] = bf2f((uint16_t)(unsigned short)v[j]);
    const float4* fp = reinterpret_cast<const float4*>(feats + base);
    float4 r0 = fp[0], r1 = fp[1];
    float4 o0, o1;
    o0.x = fmaxf(fmaf(f[0], sc0.x, sh0.x) + r0.x, 0.f);
    o0.y = fmaxf(fmaf(f[1], sc0.y, sh0.y) + r0.y, 0.f);
    o0.z = fmaxf(fmaf(f[2], sc0.z, sh0.z) + r0.z, 0.f);
    o0.w = fmaxf(fmaf(f[3], sc0.w, sh0.w) + r0.w, 0.f);
    o1.x = fmaxf(fmaf(f[4], sc1.x, sh1.x) + r1.x, 0.f);
    o1.y = fmaxf(fmaf(f[5], sc1.y, sh1.y) + r1.y, 0.f);
    o1.z = fmaxf(fmaf(f[6], sc1.z, sh1.z) + r1.z, 0.f);
    o1.w = fmaxf(fmaf(f[7], sc1.w, sh1.w) + r1.w, 0.f);
    float4* op = reinterpret_cast<float4*>(out + base);
    op[0] = o0; op[1] = o1;
}

extern "C" void kernel_launch(void* const* d_in, const int* in_sizes, int n_in,
                              void* d_out, int out_size, void* d_ws, size_t ws_size,
                              hipStream_t stream) {
    const float* feats   = (const float*)d_in[0];
    const int* in_maps   = (const int*)d_in[1];
    const int* out_maps  = (const int*)d_in[2];
    const float* W1      = (const float*)d_in[3];
    const float* gamma1  = (const float*)d_in[4];
    const float* beta1   = (const float*)d_in[5];
    const float* W2      = (const float*)d_in[6];
    const float* gamma2  = (const float*)d_in[7];
    const float* beta2   = (const float*)d_in[8];

    char* ws = (char*)d_ws;
    // ws layout (~97.2 MB, well under proven-safe ~136 MB)
    int2*     sInOut = (int2*)(ws);                               // 28,311,552 B
    uint16_t* outB   = (uint16_t*)(ws + 28311552);                // 67,108,864 B
    //   transients aliased inside outB (dead before outB memset):
    int*      counts    = (int*)(ws + 28311552);                  // 28,311,552 B
    int*      row_start = (int*)(ws + 28311552 + 28311552);       // 28,311,552 B
    uint16_t* WT1   = (uint16_t*)(ws + 95420416);                 // 884,736 B
    uint16_t* WT2   = (uint16_t*)(ws + 96305152);                 // 884,736 B
    float*    sums1 = (float*)(ws + 97189888);                    // 256 f32
    float*    sums2 = sums1 + 256;
    float*    ss1   = sums1 + 512;
    float*    ss2   = sums1 + 768;
    int*      bsum  = (int*)(ws + 97193984);                      // K*256 ints

    // featsB / bn1B live inside d_out (both dead before final_kernel writes it)
    uint16_t* featsB = (uint16_t*)d_out;                          // 67,108,864 B
    uint16_t* bn1B   = (uint16_t*)d_out + (size_t)N * C;          // 67,108,864 B

    hipMemsetAsync(counts, 0, (size_t)K * N * 4, stream);
    hipMemsetAsync(sums1, 0, 512 * 4, stream);

    cast_feats_kernel<<<N * C / 8 / 256, 256, 0, stream>>>(feats, featsB);
    transpose_w_kernel<<<K * C * C / 256, 256, 0, stream>>>(W1, W2, WT1, WT2);

    // per-k counting sort by out row
    hist_kernel<<<KM / 256, 256, 0, stream>>>(out_maps, counts);
    scan1_kernel<<<K * 256, 256, 0, stream>>>(counts, row_start, bsum);
    scan2_kernel<<<K, 256, 0, stream>>>(bsum);
    scan3_kernel<<<K * N / 256, 256, 0, stream>>>(row_start, bsum);
    scatter_kernel<<<KM / 256, 256, 0, stream>>>(in_maps, out_maps, row_start, sInOut);

    // conv1
    hipMemsetAsync(outB, 0, (size_t)N * C * 2, stream);   // clobbers counts/row_start (dead)
    gemm_kernel<<<K * TILES_PER_K, 256, 0, stream>>>(featsB, WT1, sInOut, outB);
    stats_kernel<<<1024, 256, 0, stream>>>(outB, sums1);
    finalize_kernel<<<1, 128, 0, stream>>>(sums1, gamma1, beta1, ss1);
    bnrelu_kernel<<<N * C / 8 / 256, 256, 0, stream>>>(outB, ss1, bn1B);

    // conv2
    hipMemsetAsync(outB, 0, (size_t)N * C * 2, stream);
    gemm_kernel<<<K * TILES_PER_K, 256, 0, stream>>>(bn1B, WT2, sInOut, outB);
    stats_kernel<<<1024, 256, 0, stream>>>(outB, sums2);
    finalize_kernel<<<1, 128, 0, stream>>>(sums2, gamma2, beta2, ss2);
    final_kernel<<<N * C / 8 / 256, 256, 0, stream>>>(outB, feats, ss2, (float*)d_out);
}